// Round 19
// baseline (863.620 us; speedup 1.0000x reference)
//
#include <hip/hip_runtime.h>
#include <stdint.h>

typedef unsigned short u16;
typedef __bf16 bf16x8 __attribute__((ext_vector_type(8)));
typedef float f32x4 __attribute__((ext_vector_type(4)));

#define N_TOK 16384
#define DIM   1024
#define NEXP  8
#define HID   4096
#define MT256 136           // 256-row tiles: 34816/256
#define PADROWS 34816       // 256-padded slot rows

__device__ __forceinline__ u16 f2bf(float f) {
  uint32_t u = __builtin_bit_cast(uint32_t, f);
  u += 0x7fffu + ((u >> 16) & 1u);   // RNE for finite values
  return (u16)(u >> 16);
}

__device__ __forceinline__ float bf2f(u16 v) {
  uint32_t u = (uint32_t)v << 16;
  return __builtin_bit_cast(float, u);
}

__device__ __forceinline__ void gload16(const void* g, void* l) {
  __builtin_amdgcn_global_load_lds(
      (const __attribute__((address_space(1))) uint32_t*)g,
      (__attribute__((address_space(3))) uint32_t*)l, 16, 0, 0);
}

// ---------------- init / transpose ----------------

__global__ void k_zero(int* counts) {
  if (threadIdx.x < NEXP) counts[threadIdx.x] = 0;
}

// src: [E][R][C] f32  ->  dst: [E][C][R] bf16
__global__ void k_tcast(const float* __restrict__ src, u16* __restrict__ dst,
                        int R, int C) {
  __shared__ float tile[32][33];
  int nc = C >> 5, nr = R >> 5;
  int t = blockIdx.x;
  int cb = t % nc; t /= nc;
  int rb = t % nr; int ee = t / nr;
  const float* s0 = src + ((size_t)ee * R + (size_t)rb * 32) * C + cb * 32;
  int tx = threadIdx.x & 31, ty = threadIdx.x >> 5;
#pragma unroll
  for (int i = 0; i < 4; ++i)
    tile[ty + i * 8][tx] = s0[(size_t)(ty + i * 8) * C + tx];
  __syncthreads();
  u16* d0 = dst + ((size_t)ee * C + (size_t)cb * 32) * R + rb * 32;
#pragma unroll
  for (int i = 0; i < 4; ++i)
    d0[(size_t)(ty + i * 8) * R + tx] = f2bf(tile[tx][ty + i * 8]);
}

// ---------------- gate (+ fused x -> bf16 cast); NO global atomics ----------

__global__ __launch_bounds__(256) void k_gate(
    const float* __restrict__ x, const float* __restrict__ Wg,
    const float* __restrict__ bg, u16* __restrict__ xb,
    int* __restrict__ tok_e, float* __restrict__ tok_g,
    float* __restrict__ blocksums) {
  __shared__ float wg_s[NEXP * DIM];   // transposed: [e][k]
  __shared__ float s4[4];
  for (int i = threadIdx.x; i < NEXP * DIM; i += 256) {
    int k = i >> 3, e = i & 7;
    wg_s[e * DIM + k] = Wg[i];
  }
  __syncthreads();
  int lane = threadIdx.x & 63, wv = threadIdx.x >> 6;
  int n = blockIdx.x * 4 + wv;
  const float4* xr4 = (const float4*)(x + (size_t)n * DIM);
  float4 xv[4];
#pragma unroll
  for (int i = 0; i < 4; ++i) xv[i] = xr4[lane + 64 * i];
  ushort4* xo4 = (ushort4*)(xb + (size_t)n * DIM);
#pragma unroll
  for (int i = 0; i < 4; ++i) {
    ushort4 p;
    p.x = f2bf(xv[i].x); p.y = f2bf(xv[i].y);
    p.z = f2bf(xv[i].z); p.w = f2bf(xv[i].w);
    xo4[lane + 64 * i] = p;
  }
  float acc[8];
#pragma unroll
  for (int e = 0; e < 8; ++e) {
    const float4* w4 = (const float4*)(wg_s + e * DIM);
    float a = 0.f;
#pragma unroll
    for (int i = 0; i < 4; ++i) {
      float4 wv4 = w4[lane + 64 * i];
      a += xv[i].x * wv4.x + xv[i].y * wv4.y + xv[i].z * wv4.z +
           xv[i].w * wv4.w;
    }
    acc[e] = a;
  }
#pragma unroll
  for (int e = 0; e < 8; ++e)
#pragma unroll
    for (int off = 32; off > 0; off >>= 1)
      acc[e] += __shfl_xor(acc[e], off);

  if (lane == 0) {
    float l0 = -1e30f, l1 = -1e30f; int e0 = 0, e1 = 0;
#pragma unroll
    for (int e = 0; e < 8; ++e) {
      float v = acc[e] + bg[e];
      if (v > l0) { l1 = l0; e1 = e0; l0 = v; e0 = e; }
      else if (v > l1) { l1 = v; e1 = e; }
    }
    // renormalized top-2 softmax gates depend only on the top-2 logits
    float g0 = 1.f / (1.f + expf(l1 - l0));
    float g1 = 1.f - g0;
    tok_e[2 * n] = e0; tok_e[2 * n + 1] = e1;
    tok_g[2 * n] = g0; tok_g[2 * n + 1] = g1;
    s4[wv] = g0;
  }
  __syncthreads();
  if (threadIdx.x == 0) blocksums[blockIdx.x] = s4[0] + s4[1] + s4[2] + s4[3];
}

// ---------------- histogram of tok_e: 16 blocks, 128 global atomics total ----

__global__ __launch_bounds__(256) void k_hist(const int* __restrict__ tok_e,
                                              int* __restrict__ counts) {
  __shared__ int lcnt[8];
  if (threadIdx.x < 8) lcnt[threadIdx.x] = 0;
  __syncthreads();
  int base4 = (blockIdx.x * 256 + threadIdx.x) * 2;   // 2x int4 = 8 entries
  const int4* t4 = (const int4*)tok_e;
  int4 a = t4[base4], b = t4[base4 + 1];
  int v[8] = {a.x, a.y, a.z, a.w, b.x, b.y, b.z, b.w};
  int c[8];
#pragma unroll
  for (int ee = 0; ee < 8; ++ee) {
    int s = 0;
#pragma unroll
    for (int i = 0; i < 8; ++i) s += (v[i] == ee);
    c[ee] = s;
  }
  int lane = threadIdx.x & 63;
#pragma unroll
  for (int ee = 0; ee < 8; ++ee) {
    int s = c[ee];
#pragma unroll
    for (int off = 32; off > 0; off >>= 1) s += __shfl_xor(s, off);
    if (lane == 0 && s) atomicAdd(&lcnt[ee], s);
  }
  __syncthreads();
  if (threadIdx.x < 8 && lcnt[threadIdx.x])
    atomicAdd(&counts[threadIdx.x], lcnt[threadIdx.x]);
}

// ---------------- routing setup (1 block), 256-row padding ----------------

__global__ __launch_bounds__(256) void k_setup(
    const int* __restrict__ counts, const float* __restrict__ blocksums,
    int* __restrict__ padded_off, int* __restrict__ cursor,
    int* __restrict__ row2tok, float* __restrict__ aux_out) {
  __shared__ float red[256];
  __shared__ int off_s[9];
  float s = 0.f;
  for (int i = threadIdx.x; i < 4096; i += 256) s += blocksums[i];
  red[threadIdx.x] = s;
  __syncthreads();
  for (int st = 128; st > 0; st >>= 1) {
    if (threadIdx.x < st) red[threadIdx.x] += red[threadIdx.x + st];
    __syncthreads();
  }
  if (threadIdx.x == 0) {
    int off = 0, nact = 0;
    for (int e = 0; e < 8; ++e) {
      off_s[e] = off;
      int c = counts[e];
      if (c > 0) nact++;
      off += ((c + 255) >> 8) << 8;   // pad each expert to 256-row tiles
      cursor[e] = 0;
    }
    off_s[8] = off;
    for (int e = 0; e <= 8; ++e) padded_off[e] = off_s[e];
    float m = red[0] / (float)N_TOK;
    *aux_out = (float)nact * m * m;
  }
  __syncthreads();
  // padding slots reference token 0 (valid data); no slot points at them
  for (int idx = threadIdx.x; idx < NEXP * 256; idx += 256) {
    int e = idx >> 8, i = idx & 255;
    int slot = off_s[e] + counts[e] + i;
    if (slot < off_s[e + 1]) row2tok[slot] = 0;
  }
}

// ---------------- scatter: block-aggregated; stores slots back into tok_e ----

__global__ __launch_bounds__(256) void k_scatter(
    int* __restrict__ tok_e, const int* __restrict__ padded_off,
    int* __restrict__ cursor, int* __restrict__ row2tok) {
  __shared__ int lcnt[8], lbase[8];
  if (threadIdx.x < 8) lcnt[threadIdx.x] = 0;
  __syncthreads();
  int n = blockIdx.x * 256 + threadIdx.x;
  int e0 = tok_e[2 * n], e1 = tok_e[2 * n + 1];
  int p0 = atomicAdd(&lcnt[e0], 1);
  int p1 = atomicAdd(&lcnt[e1], 1);
  __syncthreads();
  if (threadIdx.x < 8 && lcnt[threadIdx.x])
    lbase[threadIdx.x] = atomicAdd(&cursor[threadIdx.x], lcnt[threadIdx.x]);
  __syncthreads();
  int s0 = padded_off[e0] + lbase[e0] + p0;
  int s1 = padded_off[e1] + lbase[e1] + p1;
  row2tok[s0] = n;
  row2tok[s1] = n;
  tok_e[2 * n] = s0;           // tok_e now holds the slot indices
  tok_e[2 * n + 1] = s1;
}

// ---------------- grouped GEMM: 8-phase 256x256 tile, BK=64 ---------------
// m201-style schedule (T2+T3+T4+T5), proven on this problem in r18 (gemm1):
//  - 512 threads = 8 waves (2M x 4N), wave-tile 128x64, acc[8][4].
//  - LDS 128 KB: regions [tile2][khalf2] of A(256x32) and B(256x32),
//    chunk-XOR swizzled (both-sides, rule #21).
//  - Per phase: 4-8 ds_read_b128; stage ONE region; [vmcnt(6) at ph4/ph8];
//    barrier; lgkmcnt(0); sched_barrier(0); setprio(1); 16 MFMA; setprio(0);
//    barrier. Every region staged exactly 1 barrier after its last read;
//    vmcnt(6) retires exactly the tile needed by the next 4 phases.
//  - Last iter peeled: only ph1's stage issues; vmcnt(0) at its ph4.
// MODE 0: h = relu(gather(x) @ W1t[e] + b1)  (KDIM=DIM,  NDIM=HID)
// MODE 1: y = h @ W2t[e] + b2 -> y0/y1 split (KDIM=HID, NDIM=DIM)

template <int KDIM, int MODE>
__global__ __launch_bounds__(512, 2) void k_gemm_8p(
    const u16* __restrict__ Asrc, const u16* __restrict__ Wt,
    const float* __restrict__ bias, const int* __restrict__ row2tok,
    const int* __restrict__ padded_off, u16* __restrict__ out0,
    u16* __restrict__ out1) {
  __shared__ u16 ldsA[32768];   // [tile2][khalf2][256 rows][32 k]
  __shared__ u16 ldsB[32768];
  constexpr int NDIM = MODE ? DIM : HID;
  int n0 = blockIdx.x * 256;
  int row0 = blockIdx.y * 256;
  if (row0 >= padded_off[8]) return;
  int e = 0;
  while (row0 >= padded_off[e + 1]) ++e;
  int tid = threadIdx.x, lane = tid & 63, wv = tid >> 6;
  int wm = wv >> 2, wn = wv & 3;
  int fr = lane & 15, fq = lane >> 4;
  // staging: thread t -> rows (t>>2) and 128+(t>>2); physical chunk t&3 holds
  // logical chunk (t&3)^((row>>1)&3) -> pre-swizzled global source
  int r = tid >> 2;
  int clog = ((tid & 3) ^ ((tid >> 3) & 3)) * 8;
  const u16 *a0, *a1;
  if (MODE == 0) {
    a0 = Asrc + (size_t)row2tok[row0 + r] * KDIM + clog;
    a1 = Asrc + (size_t)row2tok[row0 + 128 + r] * KDIM + clog;
  } else {
    a0 = Asrc + (size_t)(row0 + r) * KDIM + clog;
    a1 = Asrc + (size_t)(row0 + 128 + r) * KDIM + clog;
  }
  const u16* wp = Wt + (size_t)e * (HID * DIM);
  const u16* b0p = wp + (size_t)(n0 + r) * KDIM + clog;
  const u16* b1p = wp + (size_t)(n0 + 128 + r) * KDIM + clog;

  f32x4 acc[8][4];
#pragma unroll
  for (int i = 0; i < 8; ++i)
#pragma unroll
    for (int j = 0; j < 4; ++j) acc[i][j] = (f32x4){0.f, 0.f, 0.f, 0.f};
  bf16x8 av[4], bv[4];

#define ST1(ISB, T, KK, KOF)                                              \
  do {                                                                   \
    u16* d_ = ((ISB) ? ldsB : ldsA) + ((T) * 2 + (KK)) * 8192 + wv * 512; \
    gload16(((ISB) ? b0p : a0) + (KOF), d_);                             \
    gload16(((ISB) ? b1p : a1) + (KOF), d_ + 4096);                      \
  } while (0)

#define RD8(T, KK, IH, LB)                                                \
  do {                                                                   \
    const u16* Ar = ldsA + ((T) * 2 + (KK)) * 8192;                      \
    _Pragma("unroll") for (int i = 0; i < 4; ++i) {                      \
      int ar = wm * 128 + ((IH) * 4 + i) * 16 + fr;                      \
      av[i] = *(const bf16x8*)&Ar[ar * 32 + ((fq ^ ((ar >> 1) & 3)) * 8)]; \
    }                                                                    \
    if (LB) {                                                            \
      const u16* Br = ldsB + ((T) * 2 + (KK)) * 8192;                    \
      _Pragma("unroll") for (int j = 0; j < 4; ++j) {                    \
        int br = wn * 64 + j * 16 + fr;                                  \
        bv[j] = *(const bf16x8*)&Br[br * 32 + ((fq ^ ((br >> 1) & 3)) * 8)]; \
      }                                                                  \
    }                                                                    \
  } while (0)

#define PH(T, KK, IH, LB, DOST, SB, STT, SKK, SKOF, VM6, VM0)            \
  do {                                                                   \
    RD8(T, KK, IH, LB);                                                  \
    if (DOST) ST1(SB, STT, SKK, SKOF);                                   \
    if (VM6) asm volatile("s_waitcnt vmcnt(6)" ::: "memory");            \
    if (VM0) asm volatile("s_waitcnt vmcnt(0)" ::: "memory");            \
    asm volatile("s_barrier" ::: "memory");                              \
    asm volatile("s_waitcnt lgkmcnt(0)" ::: "memory");                   \
    __builtin_amdgcn_sched_barrier(0);                                   \
    __builtin_amdgcn_s_setprio(1);                                       \
    _Pragma("unroll") for (int i = 0; i < 4; ++i)                        \
      _Pragma("unroll") for (int j = 0; j < 4; ++j)                      \
        acc[(IH) * 4 + i][j] = __builtin_amdgcn_mfma_f32_16x16x32_bf16(  \
            av[i], bv[j], acc[(IH) * 4 + i][j], 0, 0, 0);                \
    __builtin_amdgcn_s_setprio(0);                                       \
    asm volatile("s_barrier" ::: "memory");                              \
  } while (0)

  // prologue: tile0 complete + tile1 {Bk0, Ak0, Bk1}; leave 3 regions in flight
  ST1(1, 0, 0, 0);  ST1(0, 0, 0, 0);  ST1(1, 0, 1, 32); ST1(0, 0, 1, 32);
  ST1(1, 1, 0, 64); ST1(0, 1, 0, 64); ST1(1, 1, 1, 96);
  asm volatile("s_waitcnt vmcnt(6)" ::: "memory");
  asm volatile("s_barrier" ::: "memory");

  constexpr int NI = KDIM / 128;   // iterations, 2 K-tiles each
  for (int kt = 0; kt < NI - 1; ++kt) {
    int k0 = kt * 128;
    PH(0, 0, 0, 1, 1, 0, 1, 1, k0 + 96,  0, 0);
    PH(0, 0, 1, 0, 1, 1, 0, 0, k0 + 128, 0, 0);
    PH(0, 1, 0, 1, 1, 0, 0, 0, k0 + 128, 0, 0);
    PH(0, 1, 1, 0, 1, 1, 0, 1, k0 + 160, 1, 0);
    PH(1, 0, 0, 1, 1, 0, 0, 1, k0 + 160, 0, 0);
    PH(1, 0, 1, 0, 1, 1, 1, 0, k0 + 192, 0, 0);
    PH(1, 1, 0, 1, 1, 0, 1, 0, k0 + 192, 0, 0);
    PH(1, 1, 1, 0, 1, 1, 1, 1, k0 + 224, 1, 0);
  }
  {  // last iter: only ph1's stage (final A region); vmcnt(0) at ph4
    int k0 = (NI - 1) * 128;
    PH(0, 0, 0, 1, 1, 0, 1, 1, k0 + 96, 0, 0);
    PH(0, 0, 1, 0, 0, 0, 0, 0, 0, 0, 0);
    PH(0, 1, 0, 1, 0, 0, 0, 0, 0, 0, 0);
    PH(0, 1, 1, 0, 0, 0, 0, 0, 0, 0, 1);
    PH(1, 0, 0, 1, 0, 0, 0, 0, 0, 0, 0);
    PH(1, 0, 1, 0, 0, 0, 0, 0, 0, 0, 0);
    PH(1, 1, 0, 1, 0, 0, 0, 0, 0, 0, 0);
    PH(1, 1, 1, 0, 0, 0, 0, 0, 0, 0, 0);
  }
#undef PH
#undef RD8
#undef ST1

  float bv4[4];
#pragma unroll
  for (int j = 0; j < 4; ++j)
    bv4[j] = bias[e * NDIM + n0 + wn * 64 + j * 16 + fr];

#pragma unroll
  for (int rf = 0; rf < 8; ++rf) {
#pragma unroll
    for (int jj = 0; jj < 4; ++jj) {
      int grow = row0 + wm * 128 + rf * 16 + fq * 4 + jj;
      u16* orow;
      if (MODE == 0) {
        orow = out0 + (size_t)grow * NDIM + n0 + wn * 64 + fr;
      } else {
        orow = (grow < 16384 ? out0 + (size_t)grow * NDIM
                             : out1 + (size_t)(grow - 16384) * NDIM) +
               n0 + wn * 64 + fr;
      }
#pragma unroll
      for (int j = 0; j < 4; ++j) {
        float v = acc[rf][j][jj] + bv4[j];
        if (MODE == 0) v = v > 0.f ? v : 0.f;
        orow[j * 16] = f2bf(v);
      }
    }
  }
}

// ---------------- final combine: out[n] = g0*y[s0] + g1*y[s1] ----------------

__global__ __launch_bounds__(256) void k_combine(
    const u16* __restrict__ y0, const u16* __restrict__ y1,
    const int* __restrict__ slots, const float* __restrict__ tok_g,
    float* __restrict__ out) {
  int n = blockIdx.x;
  int s0 = slots[2 * n], s1 = slots[2 * n + 1];
  float g0 = tok_g[2 * n], g1 = tok_g[2 * n + 1];
  int d = threadIdx.x * 4;
  const u16* ya = (s0 < 16384 ? y0 + (size_t)s0 * DIM
                              : y1 + (size_t)(s0 - 16384) * DIM) + d;
  const u16* yb = (s1 < 16384 ? y0 + (size_t)s1 * DIM
                              : y1 + (size_t)(s1 - 16384) * DIM) + d;
  ushort4 a = *(const ushort4*)ya;
  ushort4 b = *(const ushort4*)yb;
  float4 o;
  o.x = g0 * bf2f(a.x) + g1 * bf2f(b.x);
  o.y = g0 * bf2f(a.y) + g1 * bf2f(b.y);
  o.z = g0 * bf2f(a.z) + g1 * bf2f(b.z);
  o.w = g0 * bf2f(a.w) + g1 * bf2f(b.w);
  *(float4*)(out + (size_t)n * DIM + d) = o;
}

// ---------------- launch ----------------

extern "C" void kernel_launch(void* const* d_in, const int* in_sizes, int n_in,
                              void* d_out, int out_size, void* d_ws,
                              size_t ws_size, hipStream_t stream) {
  const float* x  = (const float*)d_in[0];
  const float* Wg = (const float*)d_in[1];
  const float* bg = (const float*)d_in[2];
  const float* W1 = (const float*)d_in[3];
  const float* b1 = (const float*)d_in[4];
  const float* W2 = (const float*)d_in[5];
  const float* b2 = (const float*)d_in[6];
  float* out = (float*)d_out;

  // workspace layout (bytes); total ~424 MiB.
  // wT serialized: W1t for gemm1, then overwritten with W2t before gemm2.
  // y split: y0 reuses xb (dead after gemm1, 16384 rows); y1 holds the rest.
  char* w = (char*)d_ws;
  u16* xb          = (u16*)(w);                  //  33,554,432
  u16* y0          = (u16*)(w);                  //  (= xb region, after gemm1)
  u16* wT          = (u16*)(w + 33554432);       //  67,108,864
  u16* h           = (u16*)(w + 100663296);      // 285,212,672 [PADROWS][HID]
  u16* y1          = (u16*)(w + 385875968);      //  37,748,736 (18432 rows)
  int* tok_e       = (int*)(w + 423624704);      // 131,072 (experts, then slots)
  float* tok_g     = (float*)(w + 423755776);    // 131,072
  int* counts      = (int*)(w + 423886848);
  int* cursor      = (int*)(w + 423887104);
  int* padded_off  = (int*)(w + 423887360);
  int* row2tok     = (int*)(w + 423887616);      // 139,264
  float* blocksums = (float*)(w + 424026880);    // 16,384

  k_zero<<<1, 64, 0, stream>>>(counts);
  k_gate<<<4096, 256, 0, stream>>>(x, Wg, bg, xb, tok_e, tok_g, blocksums);
  k_hist<<<16, 256, 0, stream>>>(tok_e, counts);
  k_setup<<<1, 256, 0, stream>>>(counts, blocksums, padded_off, cursor, row2tok,
                                 out + (size_t)N_TOK * DIM);
  k_scatter<<<64, 256, 0, stream>>>(tok_e, padded_off, cursor, row2tok);
  k_tcast<<<32768, 256, 0, stream>>>(W1, wT, DIM, HID);
  // gemm1: 8-phase 256^2, n-fastest grid (16 n-tiles x 136 row-tiles)
  k_gemm_8p<DIM, 0><<<dim3(HID / 256, MT256), 512, 0, stream>>>(
      xb, wT, b1, row2tok, padded_off, h, nullptr);
  k_tcast<<<32768, 256, 0, stream>>>(W2, wT, HID, DIM);
  // gemm2: 8-phase 256^2, n-fastest grid (4 n-tiles x 136 row-tiles)
  k_gemm_8p<HID, 1><<<dim3(DIM / 256, MT256), 512, 0, stream>>>(
      h, wT, b2, row2tok, padded_off, y0, y1);
  k_combine<<<N_TOK, 256, 0, stream>>>(y0, y1, tok_e, tok_g, out);
}

// Round 20
// 846.212 us; speedup vs baseline: 1.0206x; 1.0206x over previous
//
#include <hip/hip_runtime.h>
#include <stdint.h>

typedef unsigned short u16;
typedef __bf16 bf16x8 __attribute__((ext_vector_type(8)));
typedef float f32x4 __attribute__((ext_vector_type(4)));

#define N_TOK 16384
#define DIM   1024
#define NEXP  8
#define HID   4096
#define MT256 136           // 256-row tiles: 34816/256 (= 8*17)
#define PADROWS 34816       // 256-padded slot rows

__device__ __forceinline__ u16 f2bf(float f) {
  uint32_t u = __builtin_bit_cast(uint32_t, f);
  u += 0x7fffu + ((u >> 16) & 1u);   // RNE for finite values
  return (u16)(u >> 16);
}

__device__ __forceinline__ float bf2f(u16 v) {
  uint32_t u = (uint32_t)v << 16;
  return __builtin_bit_cast(float, u);
}

__device__ __forceinline__ void gload16(const void* g, void* l) {
  __builtin_amdgcn_global_load_lds(
      (const __attribute__((address_space(1))) uint32_t*)g,
      (__attribute__((address_space(3))) uint32_t*)l, 16, 0, 0);
}

// ---------------- init / transpose ----------------

__global__ void k_zero(int* counts) {
  if (threadIdx.x < NEXP) counts[threadIdx.x] = 0;
}

// src: [E][R][C] f32  ->  dst: [E][C][R] bf16
__global__ void k_tcast(const float* __restrict__ src, u16* __restrict__ dst,
                        int R, int C) {
  __shared__ float tile[32][33];
  int nc = C >> 5, nr = R >> 5;
  int t = blockIdx.x;
  int cb = t % nc; t /= nc;
  int rb = t % nr; int ee = t / nr;
  const float* s0 = src + ((size_t)ee * R + (size_t)rb * 32) * C + cb * 32;
  int tx = threadIdx.x & 31, ty = threadIdx.x >> 5;
#pragma unroll
  for (int i = 0; i < 4; ++i)
    tile[ty + i * 8][tx] = s0[(size_t)(ty + i * 8) * C + tx];
  __syncthreads();
  u16* d0 = dst + ((size_t)ee * C + (size_t)cb * 32) * R + rb * 32;
#pragma unroll
  for (int i = 0; i < 4; ++i)
    d0[(size_t)(ty + i * 8) * R + tx] = f2bf(tile[tx][ty + i * 8]);
}

// ---------------- gate (+ fused x -> bf16 cast); NO global atomics ----------

__global__ __launch_bounds__(256) void k_gate(
    const float* __restrict__ x, const float* __restrict__ Wg,
    const float* __restrict__ bg, u16* __restrict__ xb,
    int* __restrict__ tok_e, float* __restrict__ tok_g,
    float* __restrict__ blocksums) {
  __shared__ float wg_s[NEXP * DIM];   // transposed: [e][k]
  __shared__ float s4[4];
  for (int i = threadIdx.x; i < NEXP * DIM; i += 256) {
    int k = i >> 3, e = i & 7;
    wg_s[e * DIM + k] = Wg[i];
  }
  __syncthreads();
  int lane = threadIdx.x & 63, wv = threadIdx.x >> 6;
  int n = blockIdx.x * 4 + wv;
  const float4* xr4 = (const float4*)(x + (size_t)n * DIM);
  float4 xv[4];
#pragma unroll
  for (int i = 0; i < 4; ++i) xv[i] = xr4[lane + 64 * i];
  ushort4* xo4 = (ushort4*)(xb + (size_t)n * DIM);
#pragma unroll
  for (int i = 0; i < 4; ++i) {
    ushort4 p;
    p.x = f2bf(xv[i].x); p.y = f2bf(xv[i].y);
    p.z = f2bf(xv[i].z); p.w = f2bf(xv[i].w);
    xo4[lane + 64 * i] = p;
  }
  float acc[8];
#pragma unroll
  for (int e = 0; e < 8; ++e) {
    const float4* w4 = (const float4*)(wg_s + e * DIM);
    float a = 0.f;
#pragma unroll
    for (int i = 0; i < 4; ++i) {
      float4 wv4 = w4[lane + 64 * i];
      a += xv[i].x * wv4.x + xv[i].y * wv4.y + xv[i].z * wv4.z +
           xv[i].w * wv4.w;
    }
    acc[e] = a;
  }
#pragma unroll
  for (int e = 0; e < 8; ++e)
#pragma unroll
    for (int off = 32; off > 0; off >>= 1)
      acc[e] += __shfl_xor(acc[e], off);

  if (lane == 0) {
    float l0 = -1e30f, l1 = -1e30f; int e0 = 0, e1 = 0;
#pragma unroll
    for (int e = 0; e < 8; ++e) {
      float v = acc[e] + bg[e];
      if (v > l0) { l1 = l0; e1 = e0; l0 = v; e0 = e; }
      else if (v > l1) { l1 = v; e1 = e; }
    }
    // renormalized top-2 softmax gates depend only on the top-2 logits
    float g0 = 1.f / (1.f + expf(l1 - l0));
    float g1 = 1.f - g0;
    tok_e[2 * n] = e0; tok_e[2 * n + 1] = e1;
    tok_g[2 * n] = g0; tok_g[2 * n + 1] = g1;
    s4[wv] = g0;
  }
  __syncthreads();
  if (threadIdx.x == 0) blocksums[blockIdx.x] = s4[0] + s4[1] + s4[2] + s4[3];
}

// ---------------- histogram of tok_e: 16 blocks, 128 global atomics total ----

__global__ __launch_bounds__(256) void k_hist(const int* __restrict__ tok_e,
                                              int* __restrict__ counts) {
  __shared__ int lcnt[8];
  if (threadIdx.x < 8) lcnt[threadIdx.x] = 0;
  __syncthreads();
  int base4 = (blockIdx.x * 256 + threadIdx.x) * 2;   // 2x int4 = 8 entries
  const int4* t4 = (const int4*)tok_e;
  int4 a = t4[base4], b = t4[base4 + 1];
  int v[8] = {a.x, a.y, a.z, a.w, b.x, b.y, b.z, b.w};
  int c[8];
#pragma unroll
  for (int ee = 0; ee < 8; ++ee) {
    int s = 0;
#pragma unroll
    for (int i = 0; i < 8; ++i) s += (v[i] == ee);
    c[ee] = s;
  }
  int lane = threadIdx.x & 63;
#pragma unroll
  for (int ee = 0; ee < 8; ++ee) {
    int s = c[ee];
#pragma unroll
    for (int off = 32; off > 0; off >>= 1) s += __shfl_xor(s, off);
    if (lane == 0 && s) atomicAdd(&lcnt[ee], s);
  }
  __syncthreads();
  if (threadIdx.x < 8 && lcnt[threadIdx.x])
    atomicAdd(&counts[threadIdx.x], lcnt[threadIdx.x]);
}

// ---------------- routing setup (1 block), 256-row padding ----------------

__global__ __launch_bounds__(256) void k_setup(
    const int* __restrict__ counts, const float* __restrict__ blocksums,
    int* __restrict__ padded_off, int* __restrict__ cursor,
    int* __restrict__ row2tok, float* __restrict__ aux_out) {
  __shared__ float red[256];
  __shared__ int off_s[9];
  float s = 0.f;
  for (int i = threadIdx.x; i < 4096; i += 256) s += blocksums[i];
  red[threadIdx.x] = s;
  __syncthreads();
  for (int st = 128; st > 0; st >>= 1) {
    if (threadIdx.x < st) red[threadIdx.x] += red[threadIdx.x + st];
    __syncthreads();
  }
  if (threadIdx.x == 0) {
    int off = 0, nact = 0;
    for (int e = 0; e < 8; ++e) {
      off_s[e] = off;
      int c = counts[e];
      if (c > 0) nact++;
      off += ((c + 255) >> 8) << 8;   // pad each expert to 256-row tiles
      cursor[e] = 0;
    }
    off_s[8] = off;
    for (int e = 0; e <= 8; ++e) padded_off[e] = off_s[e];
    float m = red[0] / (float)N_TOK;
    *aux_out = (float)nact * m * m;
  }
  __syncthreads();
  // padding slots reference token 0 (valid data); no slot points at them
  for (int idx = threadIdx.x; idx < NEXP * 256; idx += 256) {
    int e = idx >> 8, i = idx & 255;
    int slot = off_s[e] + counts[e] + i;
    if (slot < off_s[e + 1]) row2tok[slot] = 0;
  }
}

// ---------------- scatter: block-aggregated; stores slots back into tok_e ----

__global__ __launch_bounds__(256) void k_scatter(
    int* __restrict__ tok_e, const int* __restrict__ padded_off,
    int* __restrict__ cursor, int* __restrict__ row2tok) {
  __shared__ int lcnt[8], lbase[8];
  if (threadIdx.x < 8) lcnt[threadIdx.x] = 0;
  __syncthreads();
  int n = blockIdx.x * 256 + threadIdx.x;
  int e0 = tok_e[2 * n], e1 = tok_e[2 * n + 1];
  int p0 = atomicAdd(&lcnt[e0], 1);
  int p1 = atomicAdd(&lcnt[e1], 1);
  __syncthreads();
  if (threadIdx.x < 8 && lcnt[threadIdx.x])
    lbase[threadIdx.x] = atomicAdd(&cursor[threadIdx.x], lcnt[threadIdx.x]);
  __syncthreads();
  int s0 = padded_off[e0] + lbase[e0] + p0;
  int s1 = padded_off[e1] + lbase[e1] + p1;
  row2tok[s0] = n;
  row2tok[s1] = n;
  tok_e[2 * n] = s0;           // tok_e now holds the slot indices
  tok_e[2 * n + 1] = s1;
}

// ---------------- grouped GEMM: 8-phase 256x256 tile, BK=64 ---------------
// m201-style schedule (T2+T3+T4+T5), proven on this problem in r18 (gemm1):
//  - 512 threads = 8 waves (2M x 4N), wave-tile 128x64, acc[8][4].
//  - LDS 128 KB: regions [tile2][khalf2] of A(256x32) and B(256x32),
//    chunk-XOR swizzled (both-sides, rule #21).
//  - Per phase: 4-8 ds_read_b128; stage ONE region; [vmcnt(6) at ph4/ph8];
//    barrier; lgkmcnt(0); sched_barrier(0); setprio(1); 16 MFMA; setprio(0);
//    barrier. Every region staged exactly 1 barrier after its last read;
//    vmcnt(6) retires exactly the tile needed by the next 4 phases.
//  - Last iter peeled: only ph1's stage issues; vmcnt(0) at its ph4.
// Dispatch mapping (r20):
//  GRID2D=1 (gemm1): 2-D n-fastest (16x136 grid, 8.5 residency waves).
//  GRID2D=0 (gemm2): 1-D XCD-grouped, d = xcd + 8*n_t + 32*rg,
//    row-tile = rg*8+xcd -> all 4 n-siblings of a row-tile on ONE XCD,
//    concurrent -> shared 2 MB h-panel fetched once into its L2 (r14/r15
//    mechanism, applied to the 8-phase kernel).
// MODE 0: h = relu(gather(x) @ W1t[e] + b1)  (KDIM=DIM,  NDIM=HID)
// MODE 1: y = h @ W2t[e] + b2 -> y0/y1 split (KDIM=HID, NDIM=DIM)

template <int KDIM, int MODE, int GRID2D>
__global__ __launch_bounds__(512, 2) void k_gemm_8p(
    const u16* __restrict__ Asrc, const u16* __restrict__ Wt,
    const float* __restrict__ bias, const int* __restrict__ row2tok,
    const int* __restrict__ padded_off, u16* __restrict__ out0,
    u16* __restrict__ out1) {
  __shared__ u16 ldsA[32768];   // [tile2][khalf2][256 rows][32 k]
  __shared__ u16 ldsB[32768];
  constexpr int NDIM = MODE ? DIM : HID;
  int n0, row0;
  if (GRID2D) {
    n0 = blockIdx.x * 256;
    row0 = blockIdx.y * 256;
  } else {
    int d = blockIdx.x;
    int xcd = d & 7;
    int n_t = (d >> 3) & (NDIM / 256 - 1);   // NDIM/256 n-tiles (pow2)
    int rg  = d >> (3 + (NDIM == 1024 ? 2 : 4));
    n0 = n_t * 256;
    row0 = (rg * 8 + xcd) * 256;
  }
  if (row0 >= padded_off[8]) return;
  int e = 0;
  while (row0 >= padded_off[e + 1]) ++e;
  int tid = threadIdx.x, lane = tid & 63, wv = tid >> 6;
  int wm = wv >> 2, wn = wv & 3;
  int fr = lane & 15, fq = lane >> 4;
  // staging: thread t -> rows (t>>2) and 128+(t>>2); physical chunk t&3 holds
  // logical chunk (t&3)^((row>>1)&3) -> pre-swizzled global source
  int r = tid >> 2;
  int clog = ((tid & 3) ^ ((tid >> 3) & 3)) * 8;
  const u16 *a0, *a1;
  if (MODE == 0) {
    a0 = Asrc + (size_t)row2tok[row0 + r] * KDIM + clog;
    a1 = Asrc + (size_t)row2tok[row0 + 128 + r] * KDIM + clog;
  } else {
    a0 = Asrc + (size_t)(row0 + r) * KDIM + clog;
    a1 = Asrc + (size_t)(row0 + 128 + r) * KDIM + clog;
  }
  const u16* wp = Wt + (size_t)e * (HID * DIM);
  const u16* b0p = wp + (size_t)(n0 + r) * KDIM + clog;
  const u16* b1p = wp + (size_t)(n0 + 128 + r) * KDIM + clog;

  f32x4 acc[8][4];
#pragma unroll
  for (int i = 0; i < 8; ++i)
#pragma unroll
    for (int j = 0; j < 4; ++j) acc[i][j] = (f32x4){0.f, 0.f, 0.f, 0.f};
  bf16x8 av[4], bv[4];

#define ST1(ISB, T, KK, KOF)                                              \
  do {                                                                   \
    u16* d_ = ((ISB) ? ldsB : ldsA) + ((T) * 2 + (KK)) * 8192 + wv * 512; \
    gload16(((ISB) ? b0p : a0) + (KOF), d_);                             \
    gload16(((ISB) ? b1p : a1) + (KOF), d_ + 4096);                      \
  } while (0)

#define RD8(T, KK, IH, LB)                                                \
  do {                                                                   \
    const u16* Ar = ldsA + ((T) * 2 + (KK)) * 8192;                      \
    _Pragma("unroll") for (int i = 0; i < 4; ++i) {                      \
      int ar = wm * 128 + ((IH) * 4 + i) * 16 + fr;                      \
      av[i] = *(const bf16x8*)&Ar[ar * 32 + ((fq ^ ((ar >> 1) & 3)) * 8)]; \
    }                                                                    \
    if (LB) {                                                            \
      const u16* Br = ldsB + ((T) * 2 + (KK)) * 8192;                    \
      _Pragma("unroll") for (int j = 0; j < 4; ++j) {                    \
        int br = wn * 64 + j * 16 + fr;                                  \
        bv[j] = *(const bf16x8*)&Br[br * 32 + ((fq ^ ((br >> 1) & 3)) * 8)]; \
      }                                                                  \
    }                                                                    \
  } while (0)

#define PH(T, KK, IH, LB, DOST, SB, STT, SKK, SKOF, VM6, VM0)            \
  do {                                                                   \
    RD8(T, KK, IH, LB);                                                  \
    if (DOST) ST1(SB, STT, SKK, SKOF);                                   \
    if (VM6) asm volatile("s_waitcnt vmcnt(6)" ::: "memory");            \
    if (VM0) asm volatile("s_waitcnt vmcnt(0)" ::: "memory");            \
    asm volatile("s_barrier" ::: "memory");                              \
    asm volatile("s_waitcnt lgkmcnt(0)" ::: "memory");                   \
    __builtin_amdgcn_sched_barrier(0);                                   \
    __builtin_amdgcn_s_setprio(1);                                       \
    _Pragma("unroll") for (int i = 0; i < 4; ++i)                        \
      _Pragma("unroll") for (int j = 0; j < 4; ++j)                      \
        acc[(IH) * 4 + i][j] = __builtin_amdgcn_mfma_f32_16x16x32_bf16(  \
            av[i], bv[j], acc[(IH) * 4 + i][j], 0, 0, 0);                \
    __builtin_amdgcn_s_setprio(0);                                       \
    asm volatile("s_barrier" ::: "memory");                              \
  } while (0)

  // prologue: tile0 complete + tile1 {Bk0, Ak0, Bk1}; leave 3 regions in flight
  ST1(1, 0, 0, 0);  ST1(0, 0, 0, 0);  ST1(1, 0, 1, 32); ST1(0, 0, 1, 32);
  ST1(1, 1, 0, 64); ST1(0, 1, 0, 64); ST1(1, 1, 1, 96);
  asm volatile("s_waitcnt vmcnt(6)" ::: "memory");
  asm volatile("s_barrier" ::: "memory");

  constexpr int NI = KDIM / 128;   // iterations, 2 K-tiles each
  for (int kt = 0; kt < NI - 1; ++kt) {
    int k0 = kt * 128;
    PH(0, 0, 0, 1, 1, 0, 1, 1, k0 + 96,  0, 0);
    PH(0, 0, 1, 0, 1, 1, 0, 0, k0 + 128, 0, 0);
    PH(0, 1, 0, 1, 1, 0, 0, 0, k0 + 128, 0, 0);
    PH(0, 1, 1, 0, 1, 1, 0, 1, k0 + 160, 1, 0);
    PH(1, 0, 0, 1, 1, 0, 0, 1, k0 + 160, 0, 0);
    PH(1, 0, 1, 0, 1, 1, 1, 0, k0 + 192, 0, 0);
    PH(1, 1, 0, 1, 1, 0, 1, 0, k0 + 192, 0, 0);
    PH(1, 1, 1, 0, 1, 1, 1, 1, k0 + 224, 1, 0);
  }
  {  // last iter: only ph1's stage (final A region); vmcnt(0) at ph4
    int k0 = (NI - 1) * 128;
    PH(0, 0, 0, 1, 1, 0, 1, 1, k0 + 96, 0, 0);
    PH(0, 0, 1, 0, 0, 0, 0, 0, 0, 0, 0);
    PH(0, 1, 0, 1, 0, 0, 0, 0, 0, 0, 0);
    PH(0, 1, 1, 0, 0, 0, 0, 0, 0, 0, 1);
    PH(1, 0, 0, 1, 0, 0, 0, 0, 0, 0, 0);
    PH(1, 0, 1, 0, 0, 0, 0, 0, 0, 0, 0);
    PH(1, 1, 0, 1, 0, 0, 0, 0, 0, 0, 0);
    PH(1, 1, 1, 0, 0, 0, 0, 0, 0, 0, 0);
  }
#undef PH
#undef RD8
#undef ST1

  float bv4[4];
#pragma unroll
  for (int j = 0; j < 4; ++j)
    bv4[j] = bias[e * NDIM + n0 + wn * 64 + j * 16 + fr];

#pragma unroll
  for (int rf = 0; rf < 8; ++rf) {
#pragma unroll
    for (int jj = 0; jj < 4; ++jj) {
      int grow = row0 + wm * 128 + rf * 16 + fq * 4 + jj;
      u16* orow;
      if (MODE == 0) {
        orow = out0 + (size_t)grow * NDIM + n0 + wn * 64 + fr;
      } else {
        orow = (grow < 16384 ? out0 + (size_t)grow * NDIM
                             : out1 + (size_t)(grow - 16384) * NDIM) +
               n0 + wn * 64 + fr;
      }
#pragma unroll
      for (int j = 0; j < 4; ++j) {
        float v = acc[rf][j][jj] + bv4[j];
        if (MODE == 0) v = v > 0.f ? v : 0.f;
        orow[j * 16] = f2bf(v);
      }
    }
  }
}

// ---------------- final combine: out[n] = g0*y[s0] + g1*y[s1] ----------------

__global__ __launch_bounds__(256) void k_combine(
    const u16* __restrict__ y0, const u16* __restrict__ y1,
    const int* __restrict__ slots, const float* __restrict__ tok_g,
    float* __restrict__ out) {
  int n = blockIdx.x;
  int s0 = slots[2 * n], s1 = slots[2 * n + 1];
  float g0 = tok_g[2 * n], g1 = tok_g[2 * n + 1];
  int d = threadIdx.x * 4;
  const u16* ya = (s0 < 16384 ? y0 + (size_t)s0 * DIM
                              : y1 + (size_t)(s0 - 16384) * DIM) + d;
  const u16* yb = (s1 < 16384 ? y0 + (size_t)s1 * DIM
                              : y1 + (size_t)(s1 - 16384) * DIM) + d;
  ushort4 a = *(const ushort4*)ya;
  ushort4 b = *(const ushort4*)yb;
  float4 o;
  o.x = g0 * bf2f(a.x) + g1 * bf2f(b.x);
  o.y = g0 * bf2f(a.y) + g1 * bf2f(b.y);
  o.z = g0 * bf2f(a.z) + g1 * bf2f(b.z);
  o.w = g0 * bf2f(a.w) + g1 * bf2f(b.w);
  *(float4*)(out + (size_t)n * DIM + d) = o;
}

// ---------------- launch ----------------

extern "C" void kernel_launch(void* const* d_in, const int* in_sizes, int n_in,
                              void* d_out, int out_size, void* d_ws,
                              size_t ws_size, hipStream_t stream) {
  const float* x  = (const float*)d_in[0];
  const float* Wg = (const float*)d_in[1];
  const float* bg = (const float*)d_in[2];
  const float* W1 = (const float*)d_in[3];
  const float* b1 = (const float*)d_in[4];
  const float* W2 = (const float*)d_in[5];
  const float* b2 = (const float*)d_in[6];
  float* out = (float*)d_out;

  // workspace layout (bytes); total ~424 MiB.
  // wT serialized: W1t for gemm1, then overwritten with W2t before gemm2.
  // y split: y0 reuses xb (dead after gemm1, 16384 rows); y1 holds the rest.
  char* w = (char*)d_ws;
  u16* xb          = (u16*)(w);                  //  33,554,432
  u16* y0          = (u16*)(w);                  //  (= xb region, after gemm1)
  u16* wT          = (u16*)(w + 33554432);       //  67,108,864
  u16* h           = (u16*)(w + 100663296);      // 285,212,672 [PADROWS][HID]
  u16* y1          = (u16*)(w + 385875968);      //  37,748,736 (18432 rows)
  int* tok_e       = (int*)(w + 423624704);      // 131,072 (experts, then slots)
  float* tok_g     = (float*)(w + 423755776);    // 131,072
  int* counts      = (int*)(w + 423886848);
  int* cursor      = (int*)(w + 423887104);
  int* padded_off  = (int*)(w + 423887360);
  int* row2tok     = (int*)(w + 423887616);      // 139,264
  float* blocksums = (float*)(w + 424026880);    // 16,384

  k_zero<<<1, 64, 0, stream>>>(counts);
  k_gate<<<4096, 256, 0, stream>>>(x, Wg, bg, xb, tok_e, tok_g, blocksums);
  k_hist<<<16, 256, 0, stream>>>(tok_e, counts);
  k_setup<<<1, 256, 0, stream>>>(counts, blocksums, padded_off, cursor, row2tok,
                                 out + (size_t)N_TOK * DIM);
  k_scatter<<<64, 256, 0, stream>>>(tok_e, padded_off, cursor, row2tok);
  k_tcast<<<32768, 256, 0, stream>>>(W1, wT, DIM, HID);
  // gemm1: 8-phase 256^2, 2-D n-fastest grid (16 n-tiles x 136 row-tiles)
  k_gemm_8p<DIM, 0, 1><<<dim3(HID / 256, MT256), 512, 0, stream>>>(
      xb, wT, b1, row2tok, padded_off, h, nullptr);
  k_tcast<<<32768, 256, 0, stream>>>(W2, wT, HID, DIM);
  // gemm2: 8-phase 256^2, 1-D XCD-grouped (4 n-siblings per row-tile on one
  // XCD -> h-panel L2 reuse); 544 = 8 * 4 * 17 blocks
  k_gemm_8p<HID, 1, 0><<<MT256 * (DIM / 256), 512, 0, stream>>>(
      h, wT, b2, row2tok, padded_off, y0, y1);
  k_combine<<<N_TOK, 256, 0, stream>>>(y0, y1, tok_e, tok_g, out);
}

// Round 21
// 826.776 us; speedup vs baseline: 1.0446x; 1.0235x over previous
//
#include <hip/hip_runtime.h>
#include <stdint.h>

typedef unsigned short u16;
typedef __bf16 bf16x8 __attribute__((ext_vector_type(8)));
typedef float f32x4 __attribute__((ext_vector_type(4)));

#define N_TOK 16384
#define DIM   1024
#define NEXP  8
#define HID   4096
#define MT256 136           // 256-row tiles: 34816/256
#define MT128 272           // 128-row tiles: 34816/128 (div by 8)
#define PADROWS 34816       // 256-padded slot rows

__device__ __forceinline__ u16 f2bf(float f) {
  uint32_t u = __builtin_bit_cast(uint32_t, f);
  u += 0x7fffu + ((u >> 16) & 1u);   // RNE for finite values
  return (u16)(u >> 16);
}

__device__ __forceinline__ float bf2f(u16 v) {
  uint32_t u = (uint32_t)v << 16;
  return __builtin_bit_cast(float, u);
}

__device__ __forceinline__ void gload16(const void* g, void* l) {
  __builtin_amdgcn_global_load_lds(
      (const __attribute__((address_space(1))) uint32_t*)g,
      (__attribute__((address_space(3))) uint32_t*)l, 16, 0, 0);
}

// ---------------- init / transpose ----------------

__global__ void k_zero(int* counts) {
  if (threadIdx.x < NEXP) counts[threadIdx.x] = 0;
}

// src: [E][R][C] f32  ->  dst: [E][C][R] bf16.  Vectorized (G13):
// float4 loads (16B/lane), ushort4 stores (8B/lane), single-shot 32x32 tile.
__global__ __launch_bounds__(256) void k_tcast(const float* __restrict__ src,
                                               u16* __restrict__ dst, int R,
                                               int C) {
  __shared__ float tile[32][33];
  int nc = C >> 5, nr = R >> 5;
  int t = blockIdx.x;
  int cb = t % nc; t /= nc;
  int rb = t % nr; int ee = t / nr;
  const float* s0 = src + ((size_t)ee * R + (size_t)rb * 32) * C + cb * 32;
  int tid = threadIdx.x;
  {
    int lr = tid >> 3, lc = (tid & 7) * 4;
    float4 v = *(const float4*)(s0 + (size_t)lr * C + lc);
    tile[lr][lc] = v.x; tile[lr][lc + 1] = v.y;
    tile[lr][lc + 2] = v.z; tile[lr][lc + 3] = v.w;
  }
  __syncthreads();
  u16* d0 = dst + ((size_t)ee * C + (size_t)cb * 32) * R + rb * 32;
  {
    int c = tid >> 3, rq = (tid & 7) * 4;
    ushort4 p;
    p.x = f2bf(tile[rq][c]);     p.y = f2bf(tile[rq + 1][c]);
    p.z = f2bf(tile[rq + 2][c]); p.w = f2bf(tile[rq + 3][c]);
    *(ushort4*)(d0 + (size_t)c * R + rq) = p;
  }
}

// ---------------- gate (+ fused x -> bf16 cast); NO global atomics ----------

__global__ __launch_bounds__(256) void k_gate(
    const float* __restrict__ x, const float* __restrict__ Wg,
    const float* __restrict__ bg, u16* __restrict__ xb,
    int* __restrict__ tok_e, float* __restrict__ tok_g,
    float* __restrict__ blocksums) {
  __shared__ float wg_s[NEXP * DIM];   // transposed: [e][k]
  __shared__ float s4[4];
  for (int i = threadIdx.x; i < NEXP * DIM; i += 256) {
    int k = i >> 3, e = i & 7;
    wg_s[e * DIM + k] = Wg[i];
  }
  __syncthreads();
  int lane = threadIdx.x & 63, wv = threadIdx.x >> 6;
  int n = blockIdx.x * 4 + wv;
  const float4* xr4 = (const float4*)(x + (size_t)n * DIM);
  float4 xv[4];
#pragma unroll
  for (int i = 0; i < 4; ++i) xv[i] = xr4[lane + 64 * i];
  ushort4* xo4 = (ushort4*)(xb + (size_t)n * DIM);
#pragma unroll
  for (int i = 0; i < 4; ++i) {
    ushort4 p;
    p.x = f2bf(xv[i].x); p.y = f2bf(xv[i].y);
    p.z = f2bf(xv[i].z); p.w = f2bf(xv[i].w);
    xo4[lane + 64 * i] = p;
  }
  float acc[8];
#pragma unroll
  for (int e = 0; e < 8; ++e) {
    const float4* w4 = (const float4*)(wg_s + e * DIM);
    float a = 0.f;
#pragma unroll
    for (int i = 0; i < 4; ++i) {
      float4 wv4 = w4[lane + 64 * i];
      a += xv[i].x * wv4.x + xv[i].y * wv4.y + xv[i].z * wv4.z +
           xv[i].w * wv4.w;
    }
    acc[e] = a;
  }
#pragma unroll
  for (int e = 0; e < 8; ++e)
#pragma unroll
    for (int off = 32; off > 0; off >>= 1)
      acc[e] += __shfl_xor(acc[e], off);

  if (lane == 0) {
    float l0 = -1e30f, l1 = -1e30f; int e0 = 0, e1 = 0;
#pragma unroll
    for (int e = 0; e < 8; ++e) {
      float v = acc[e] + bg[e];
      if (v > l0) { l1 = l0; e1 = e0; l0 = v; e0 = e; }
      else if (v > l1) { l1 = v; e1 = e; }
    }
    // renormalized top-2 softmax gates depend only on the top-2 logits
    float g0 = 1.f / (1.f + expf(l1 - l0));
    float g1 = 1.f - g0;
    tok_e[2 * n] = e0; tok_e[2 * n + 1] = e1;
    tok_g[2 * n] = g0; tok_g[2 * n + 1] = g1;
    s4[wv] = g0;
  }
  __syncthreads();
  if (threadIdx.x == 0) blocksums[blockIdx.x] = s4[0] + s4[1] + s4[2] + s4[3];
}

// ---------------- histogram of tok_e: 16 blocks, 128 global atomics total ----

__global__ __launch_bounds__(256) void k_hist(const int* __restrict__ tok_e,
                                              int* __restrict__ counts) {
  __shared__ int lcnt[8];
  if (threadIdx.x < 8) lcnt[threadIdx.x] = 0;
  __syncthreads();
  int base4 = (blockIdx.x * 256 + threadIdx.x) * 2;   // 2x int4 = 8 entries
  const int4* t4 = (const int4*)tok_e;
  int4 a = t4[base4], b = t4[base4 + 1];
  int v[8] = {a.x, a.y, a.z, a.w, b.x, b.y, b.z, b.w};
  int c[8];
#pragma unroll
  for (int ee = 0; ee < 8; ++ee) {
    int s = 0;
#pragma unroll
    for (int i = 0; i < 8; ++i) s += (v[i] == ee);
    c[ee] = s;
  }
  int lane = threadIdx.x & 63;
#pragma unroll
  for (int ee = 0; ee < 8; ++ee) {
    int s = c[ee];
#pragma unroll
    for (int off = 32; off > 0; off >>= 1) s += __shfl_xor(s, off);
    if (lane == 0 && s) atomicAdd(&lcnt[ee], s);
  }
  __syncthreads();
  if (threadIdx.x < 8 && lcnt[threadIdx.x])
    atomicAdd(&counts[threadIdx.x], lcnt[threadIdx.x]);
}

// ---------------- routing setup (1 block), 256-row padding ----------------

__global__ __launch_bounds__(256) void k_setup(
    const int* __restrict__ counts, const float* __restrict__ blocksums,
    int* __restrict__ padded_off, int* __restrict__ cursor,
    int* __restrict__ row2tok, float* __restrict__ aux_out) {
  __shared__ float red[256];
  __shared__ int off_s[9];
  float s = 0.f;
  for (int i = threadIdx.x; i < 4096; i += 256) s += blocksums[i];
  red[threadIdx.x] = s;
  __syncthreads();
  for (int st = 128; st > 0; st >>= 1) {
    if (threadIdx.x < st) red[threadIdx.x] += red[threadIdx.x + st];
    __syncthreads();
  }
  if (threadIdx.x == 0) {
    int off = 0, nact = 0;
    for (int e = 0; e < 8; ++e) {
      off_s[e] = off;
      int c = counts[e];
      if (c > 0) nact++;
      off += ((c + 255) >> 8) << 8;   // pad each expert to 256-row tiles
      cursor[e] = 0;
    }
    off_s[8] = off;
    for (int e = 0; e <= 8; ++e) padded_off[e] = off_s[e];
    float m = red[0] / (float)N_TOK;
    *aux_out = (float)nact * m * m;
  }
  __syncthreads();
  // padding slots reference token 0 (valid data); no slot points at them
  for (int idx = threadIdx.x; idx < NEXP * 256; idx += 256) {
    int e = idx >> 8, i = idx & 255;
    int slot = off_s[e] + counts[e] + i;
    if (slot < off_s[e + 1]) row2tok[slot] = 0;
  }
}

// ---------------- scatter: block-aggregated; stores slots back into tok_e ----

__global__ __launch_bounds__(256) void k_scatter(
    int* __restrict__ tok_e, const int* __restrict__ padded_off,
    int* __restrict__ cursor, int* __restrict__ row2tok) {
  __shared__ int lcnt[8], lbase[8];
  if (threadIdx.x < 8) lcnt[threadIdx.x] = 0;
  __syncthreads();
  int n = blockIdx.x * 256 + threadIdx.x;
  int e0 = tok_e[2 * n], e1 = tok_e[2 * n + 1];
  int p0 = atomicAdd(&lcnt[e0], 1);
  int p1 = atomicAdd(&lcnt[e1], 1);
  __syncthreads();
  if (threadIdx.x < 8 && lcnt[threadIdx.x])
    lbase[threadIdx.x] = atomicAdd(&cursor[threadIdx.x], lcnt[threadIdx.x]);
  __syncthreads();
  int s0 = padded_off[e0] + lbase[e0] + p0;
  int s1 = padded_off[e1] + lbase[e1] + p1;
  row2tok[s0] = n;
  row2tok[s1] = n;
  tok_e[2 * n] = s0;           // tok_e now holds the slot indices
  tok_e[2 * n + 1] = s1;
}

// ---------------- gemm1: 8-phase 256x256 tile, BK=64, 2 K-tiles/iter ------
// m201-style schedule (T2+T3+T4+T5), proven on this problem in r18:
//  - 512 threads = 8 waves (2M x 4N), wave-tile 128x64, acc[8][4].
//  - LDS 128 KB: regions [tile2][khalf2] of A(256x32) and B(256x32),
//    chunk-XOR swizzled (both-sides, rule #21).
//  - Per phase: 4-8 ds_read_b128; stage ONE region; [vmcnt(6) at ph4/ph8];
//    barrier; lgkmcnt(0); sched_barrier(0); setprio(1); 16 MFMA; setprio(0);
//    barrier. Every region staged exactly 1 barrier after its last read;
//    vmcnt(6) retires exactly the tile needed by the next 4 phases.
//  - Last iter peeled: only ph1's stage issues; vmcnt(0) at its ph4.
// h = relu(gather(x) @ W1t[e] + b1).

__global__ __launch_bounds__(512, 2) void k_gemm1_8p(
    const u16* __restrict__ xb, const u16* __restrict__ w1t,
    const float* __restrict__ b1, const int* __restrict__ row2tok,
    const int* __restrict__ padded_off, u16* __restrict__ h) {
  __shared__ u16 ldsA[32768];   // [tile2][khalf2][256 rows][32 k]
  __shared__ u16 ldsB[32768];
  int n0 = blockIdx.x * 256;
  int row0 = blockIdx.y * 256;
  if (row0 >= padded_off[8]) return;
  int e = 0;
  while (row0 >= padded_off[e + 1]) ++e;
  int tid = threadIdx.x, lane = tid & 63, wv = tid >> 6;
  int wm = wv >> 2, wn = wv & 3;
  int fr = lane & 15, fq = lane >> 4;
  int r = tid >> 2;
  int clog = ((tid & 3) ^ ((tid >> 3) & 3)) * 8;
  const u16* a0 = xb + (size_t)row2tok[row0 + r] * DIM + clog;
  const u16* a1 = xb + (size_t)row2tok[row0 + 128 + r] * DIM + clog;
  const u16* wp = w1t + (size_t)e * (HID * DIM);
  const u16* b0p = wp + (size_t)(n0 + r) * DIM + clog;
  const u16* b1p = wp + (size_t)(n0 + 128 + r) * DIM + clog;

  f32x4 acc[8][4];
#pragma unroll
  for (int i = 0; i < 8; ++i)
#pragma unroll
    for (int j = 0; j < 4; ++j) acc[i][j] = (f32x4){0.f, 0.f, 0.f, 0.f};
  bf16x8 av[4], bv[4];

#define ST1(ISB, T, KK, KOF)                                              \
  do {                                                                   \
    u16* d_ = ((ISB) ? ldsB : ldsA) + ((T) * 2 + (KK)) * 8192 + wv * 512; \
    gload16(((ISB) ? b0p : a0) + (KOF), d_);                             \
    gload16(((ISB) ? b1p : a1) + (KOF), d_ + 4096);                      \
  } while (0)

#define RD8(T, KK, IH, LB)                                                \
  do {                                                                   \
    const u16* Ar = ldsA + ((T) * 2 + (KK)) * 8192;                      \
    _Pragma("unroll") for (int i = 0; i < 4; ++i) {                      \
      int ar = wm * 128 + ((IH) * 4 + i) * 16 + fr;                      \
      av[i] = *(const bf16x8*)&Ar[ar * 32 + ((fq ^ ((ar >> 1) & 3)) * 8)]; \
    }                                                                    \
    if (LB) {                                                            \
      const u16* Br = ldsB + ((T) * 2 + (KK)) * 8192;                    \
      _Pragma("unroll") for (int j = 0; j < 4; ++j) {                    \
        int br = wn * 64 + j * 16 + fr;                                  \
        bv[j] = *(const bf16x8*)&Br[br * 32 + ((fq ^ ((br >> 1) & 3)) * 8)]; \
      }                                                                  \
    }                                                                    \
  } while (0)

#define PH(T, KK, IH, LB, DOST, SB, STT, SKK, SKOF, VM6, VM0)            \
  do {                                                                   \
    RD8(T, KK, IH, LB);                                                  \
    if (DOST) ST1(SB, STT, SKK, SKOF);                                   \
    if (VM6) asm volatile("s_waitcnt vmcnt(6)" ::: "memory");            \
    if (VM0) asm volatile("s_waitcnt vmcnt(0)" ::: "memory");            \
    asm volatile("s_barrier" ::: "memory");                              \
    asm volatile("s_waitcnt lgkmcnt(0)" ::: "memory");                   \
    __builtin_amdgcn_sched_barrier(0);                                   \
    __builtin_amdgcn_s_setprio(1);                                       \
    _Pragma("unroll") for (int i = 0; i < 4; ++i)                        \
      _Pragma("unroll") for (int j = 0; j < 4; ++j)                      \
        acc[(IH) * 4 + i][j] = __builtin_amdgcn_mfma_f32_16x16x32_bf16(  \
            av[i], bv[j], acc[(IH) * 4 + i][j], 0, 0, 0);                \
    __builtin_amdgcn_s_setprio(0);                                       \
    asm volatile("s_barrier" ::: "memory");                              \
  } while (0)

  // prologue: tile0 complete + tile1 {Bk0, Ak0, Bk1}; leave 3 regions in flight
  ST1(1, 0, 0, 0);  ST1(0, 0, 0, 0);  ST1(1, 0, 1, 32); ST1(0, 0, 1, 32);
  ST1(1, 1, 0, 64); ST1(0, 1, 0, 64); ST1(1, 1, 1, 96);
  asm volatile("s_waitcnt vmcnt(6)" ::: "memory");
  asm volatile("s_barrier" ::: "memory");

  constexpr int NI = DIM / 128;   // 8 iterations, 2 K-tiles each
  for (int kt = 0; kt < NI - 1; ++kt) {
    int k0 = kt * 128;
    PH(0, 0, 0, 1, 1, 0, 1, 1, k0 + 96,  0, 0);
    PH(0, 0, 1, 0, 1, 1, 0, 0, k0 + 128, 0, 0);
    PH(0, 1, 0, 1, 1, 0, 0, 0, k0 + 128, 0, 0);
    PH(0, 1, 1, 0, 1, 1, 0, 1, k0 + 160, 1, 0);
    PH(1, 0, 0, 1, 1, 0, 0, 1, k0 + 160, 0, 0);
    PH(1, 0, 1, 0, 1, 1, 1, 0, k0 + 192, 0, 0);
    PH(1, 1, 0, 1, 1, 0, 1, 0, k0 + 192, 0, 0);
    PH(1, 1, 1, 0, 1, 1, 1, 1, k0 + 224, 1, 0);
  }
  {  // last iter: only ph1's stage (final A region); vmcnt(0) at ph4
    int k0 = (NI - 1) * 128;
    PH(0, 0, 0, 1, 1, 0, 1, 1, k0 + 96, 0, 0);
    PH(0, 0, 1, 0, 0, 0, 0, 0, 0, 0, 0);
    PH(0, 1, 0, 1, 0, 0, 0, 0, 0, 0, 0);
    PH(0, 1, 1, 0, 0, 0, 0, 0, 0, 0, 1);
    PH(1, 0, 0, 1, 0, 0, 0, 0, 0, 0, 0);
    PH(1, 0, 1, 0, 0, 0, 0, 0, 0, 0, 0);
    PH(1, 1, 0, 1, 0, 0, 0, 0, 0, 0, 0);
    PH(1, 1, 1, 0, 0, 0, 0, 0, 0, 0, 0);
  }
#undef PH
#undef RD8
#undef ST1

  float bv4[4];
#pragma unroll
  for (int j = 0; j < 4; ++j)
    bv4[j] = b1[e * HID + n0 + wn * 64 + j * 16 + fr];

#pragma unroll
  for (int rf = 0; rf < 8; ++rf) {
#pragma unroll
    for (int jj = 0; jj < 4; ++jj) {
      int grow = row0 + wm * 128 + rf * 16 + fq * 4 + jj;
      u16* hr = h + (size_t)grow * HID + n0 + wn * 64 + fr;
#pragma unroll
      for (int j = 0; j < 4; ++j) {
        float v = acc[rf][j][jj] + bv4[j];
        hr[j * 16] = f2bf(v > 0.f ? v : 0.f);
      }
    }
  }
}

// ---------------- gemm2: r15-exact 128x128, counted-vmcnt, XCD-grouped ----
// y = h @ W2t[e] + b2 (bf16, split across y0/y1 regions).

__global__ __launch_bounds__(256, 3) void k_gemm2(
    const u16* __restrict__ hh, const u16* __restrict__ w2t,
    const float* __restrict__ b2, const int* __restrict__ padded_off,
    u16* __restrict__ y0, u16* __restrict__ y1) {
  __shared__ u16 Abuf[3][4096];
  __shared__ u16 Bbuf[3][4096];
  int d = blockIdx.x;
  int xcd = d & 7;
  int n_t = (d >> 3) & 7;           // 8 n-tiles
  int rg  = d >> 6;
  int row0 = (rg * 8 + xcd) * 128;
  if (row0 >= padded_off[8]) return;
  int e = 0;
  while (row0 >= padded_off[e + 1]) ++e;
  int n0 = n_t * 128;
  int tid = threadIdx.x, lane = tid & 63, wv = tid >> 6;
  int wm = wv >> 1, wn = wv & 1;
  int fr = lane & 15, fq = lane >> 4;
  int ra0 = tid >> 2, ra1 = 64 + (tid >> 2);
  int ca = (((tid & 3) ^ ((tid >> 3) & 3))) * 8;
  const u16* asrc0 = hh + (size_t)(row0 + ra0) * HID + ca;
  const u16* asrc1 = hh + (size_t)(row0 + ra1) * HID + ca;
  const u16* bb = w2t + (size_t)e * (HID * DIM);
  const u16* bsrc0 = bb + (size_t)(n0 + ra0) * HID + ca;
  const u16* bsrc1 = bb + (size_t)(n0 + ra1) * HID + ca;
  int lo = wv * 512;
  int sq = (fq ^ ((fr >> 1) & 3)) * 8;

  f32x4 acc[4][4];
#pragma unroll
  for (int i = 0; i < 4; ++i)
#pragma unroll
    for (int j = 0; j < 4; ++j) acc[i][j] = (f32x4){0.f, 0.f, 0.f, 0.f};
  bf16x8 av[4], bv[4];

#define STG(b, kt)                                 \
  do {                                             \
    int ko = (kt) * 32;                            \
    gload16(asrc0 + ko, &Abuf[b][lo]);             \
    gload16(asrc1 + ko, &Abuf[b][2048 + lo]);      \
    gload16(bsrc0 + ko, &Bbuf[b][lo]);             \
    gload16(bsrc1 + ko, &Bbuf[b][2048 + lo]);      \
  } while (0)

#define CMP(b)                                                                 \
  do {                                                                         \
    _Pragma("unroll") for (int fm = 0; fm < 4; ++fm)                           \
        av[fm] = *(const bf16x8*)&Abuf[b][(wm * 64 + fm * 16 + fr) * 32 + sq]; \
    _Pragma("unroll") for (int fn = 0; fn < 4; ++fn)                           \
        bv[fn] = *(const bf16x8*)&Bbuf[b][(wn * 64 + fn * 16 + fr) * 32 + sq]; \
    _Pragma("unroll") for (int fm = 0; fm < 4; ++fm)                           \
        _Pragma("unroll") for (int fn = 0; fn < 4; ++fn)                       \
            acc[fm][fn] = __builtin_amdgcn_mfma_f32_16x16x32_bf16(             \
                av[fm], bv[fn], acc[fm][fn], 0, 0, 0);                         \
  } while (0)

  constexpr int NK = HID / 32;
  STG(0, 0);
  STG(1, 1);
  int rb = 0;
  for (int kt = 0; kt < NK - 2; ++kt) {
    int sb = rb + 2; if (sb >= 3) sb -= 3;
    STG(sb, kt + 2);
    asm volatile("s_waitcnt vmcnt(8)" ::: "memory");
    asm volatile("s_barrier" ::: "memory");
    CMP(rb);
    asm volatile("s_waitcnt lgkmcnt(0)" ::: "memory");
    asm volatile("s_barrier" ::: "memory");
    if (++rb == 3) rb = 0;
  }
  asm volatile("s_waitcnt vmcnt(4)" ::: "memory");
  asm volatile("s_barrier" ::: "memory");
  CMP(rb);
  if (++rb == 3) rb = 0;
  asm volatile("s_waitcnt vmcnt(0)" ::: "memory");
  asm volatile("s_barrier" ::: "memory");
  CMP(rb);
#undef STG
#undef CMP

  float bv4[4];
#pragma unroll
  for (int fn = 0; fn < 4; ++fn)
    bv4[fn] = b2[e * DIM + n0 + wn * 64 + fn * 16 + fr];

#pragma unroll
  for (int fm = 0; fm < 4; ++fm) {
#pragma unroll
    for (int j = 0; j < 4; ++j) {
      int grow = row0 + wm * 64 + fm * 16 + fq * 4 + j;
      u16* ybase = grow < 16384 ? y0 + (size_t)grow * DIM
                                : y1 + (size_t)(grow - 16384) * DIM;
      u16* orow = ybase + n0 + wn * 64 + fr;
#pragma unroll
      for (int fn = 0; fn < 4; ++fn)
        orow[fn * 16] = f2bf(acc[fm][fn][j] + bv4[fn]);
    }
  }
}

// ---------------- final combine: out[n] = g0*y[s0] + g1*y[s1] ----------------

__global__ __launch_bounds__(256) void k_combine(
    const u16* __restrict__ y0, const u16* __restrict__ y1,
    const int* __restrict__ slots, const float* __restrict__ tok_g,
    float* __restrict__ out) {
  int n = blockIdx.x;
  int s0 = slots[2 * n], s1 = slots[2 * n + 1];
  float g0 = tok_g[2 * n], g1 = tok_g[2 * n + 1];
  int d = threadIdx.x * 4;
  const u16* ya = (s0 < 16384 ? y0 + (size_t)s0 * DIM
                              : y1 + (size_t)(s0 - 16384) * DIM) + d;
  const u16* yb = (s1 < 16384 ? y0 + (size_t)s1 * DIM
                              : y1 + (size_t)(s1 - 16384) * DIM) + d;
  ushort4 a = *(const ushort4*)ya;
  ushort4 b = *(const ushort4*)yb;
  float4 o;
  o.x = g0 * bf2f(a.x) + g1 * bf2f(b.x);
  o.y = g0 * bf2f(a.y) + g1 * bf2f(b.y);
  o.z = g0 * bf2f(a.z) + g1 * bf2f(b.z);
  o.w = g0 * bf2f(a.w) + g1 * bf2f(b.w);
  *(float4*)(out + (size_t)n * DIM + d) = o;
}

// ---------------- launch ----------------

extern "C" void kernel_launch(void* const* d_in, const int* in_sizes, int n_in,
                              void* d_out, int out_size, void* d_ws,
                              size_t ws_size, hipStream_t stream) {
  const float* x  = (const float*)d_in[0];
  const float* Wg = (const float*)d_in[1];
  const float* bg = (const float*)d_in[2];
  const float* W1 = (const float*)d_in[3];
  const float* b1 = (const float*)d_in[4];
  const float* W2 = (const float*)d_in[5];
  const float* b2 = (const float*)d_in[6];
  float* out = (float*)d_out;

  // workspace layout (bytes); total ~424 MiB.
  // wT serialized: W1t for gemm1, then overwritten with W2t before gemm2.
  // y split: y0 reuses xb (dead after gemm1, 16384 rows); y1 holds the rest.
  char* w = (char*)d_ws;
  u16* xb          = (u16*)(w);                  //  33,554,432
  u16* y0          = (u16*)(w);                  //  (= xb region, after gemm1)
  u16* wT          = (u16*)(w + 33554432);       //  67,108,864
  u16* h           = (u16*)(w + 100663296);      // 285,212,672 [PADROWS][HID]
  u16* y1          = (u16*)(w + 385875968);      //  37,748,736 (18432 rows)
  int* tok_e       = (int*)(w + 423624704);      // 131,072 (experts, then slots)
  float* tok_g     = (float*)(w + 423755776);    // 131,072
  int* counts      = (int*)(w + 423886848);
  int* cursor      = (int*)(w + 423887104);
  int* padded_off  = (int*)(w + 423887360);
  int* row2tok     = (int*)(w + 423887616);      // 139,264
  float* blocksums = (float*)(w + 424026880);    // 16,384

  k_zero<<<1, 64, 0, stream>>>(counts);
  k_gate<<<4096, 256, 0, stream>>>(x, Wg, bg, xb, tok_e, tok_g, blocksums);
  k_hist<<<16, 256, 0, stream>>>(tok_e, counts);
  k_setup<<<1, 256, 0, stream>>>(counts, blocksums, padded_off, cursor, row2tok,
                                 out + (size_t)N_TOK * DIM);
  k_scatter<<<64, 256, 0, stream>>>(tok_e, padded_off, cursor, row2tok);
  k_tcast<<<32768, 256, 0, stream>>>(W1, wT, DIM, HID);
  // gemm1: 8-phase 256^2, 2-D n-fastest grid (16 n-tiles x 136 row-tiles)
  k_gemm1_8p<<<dim3(HID / 256, MT256), 512, 0, stream>>>(
      xb, wT, b1, row2tok, padded_off, h);
  k_tcast<<<32768, 256, 0, stream>>>(W2, wT, HID, DIM);
  // gemm2: r15-exact 128^2, 1-D XCD-grouped (A-panel L2 reuse)
  k_gemm2<<<MT128 * (DIM / 128), 256, 0, stream>>>(
      h, wT, b2, padded_off, y0, y1);
  k_combine<<<N_TOK, 256, 0, stream>>>(y0, y1, tok_e, tok_g, out);
}